// Round 3
// baseline (12749.722 us; speedup 1.0000x reference)
//
#include <hip/hip_runtime.h>
#include <hip/hip_bf16.h>

#define BTOT 65536
#define TT   30
#define HH   32

__device__ __forceinline__ float fast_tanh(float v) {
    // tanh(v) = 1 - 2/(exp(2v)+1); exp(2v) = exp2(v * 2*log2(e))
    float e = __builtin_amdgcn_exp2f(v * 2.885390081777927f);
    float r = __builtin_amdgcn_rcpf(e + 1.0f);
    return fmaf(-2.0f, r, 1.0f);
}

// ---------------- RNN: all 5 layers fused, 1 thread = 1 sample ----------------
// Writes Y chunk-local, feature-major: Y[(t*32+j)*Bs + (b-base)]
__global__ __launch_bounds__(256, 1) void rnn_kernel(
    const float* __restrict__ x, const float* __restrict__ h0,
    const float* __restrict__ Wih0, const float* __restrict__ WihR,
    const float* __restrict__ Whh, const float* __restrict__ bih,
    const float* __restrict__ bhh, float* __restrict__ Y,
    int base, int Bs)
{
    const int bl = blockIdx.x * 256 + threadIdx.x;  // chunk-local sample
    const int b  = base + bl;                       // global sample
    float h[5][32];
#pragma unroll
    for (int l = 0; l < 5; ++l)
#pragma unroll
        for (int j = 0; j < 32; ++j)
            h[l][j] = h0[((size_t)l * BTOT + b) * HH + j];

    const float* xb = x + (size_t)b * (TT * 3);

#pragma unroll 1
    for (int t = 0; t < TT; ++t) {
        const float in0 = xb[t * 3 + 0];
        const float in1 = xb[t * 3 + 1];
        const float in2 = xb[t * 3 + 2];
        float y[32];
        // ---- layer 0 (input dim 3) ----
#pragma unroll
        for (int j = 0; j < 32; ++j) {
            float a = bih[j] + bhh[j];
            a = fmaf(Wih0[j * 3 + 0], in0, a);
            a = fmaf(Wih0[j * 3 + 1], in1, a);
            a = fmaf(Wih0[j * 3 + 2], in2, a);
#pragma unroll
            for (int k = 0; k < 32; ++k)
                a = fmaf(Whh[j * 32 + k], h[0][k], a);
            y[j] = fast_tanh(a);
        }
#pragma unroll
        for (int j = 0; j < 32; ++j) h[0][j] = y[j];
        // ---- layers 1..4 ----
#pragma unroll
        for (int l = 1; l < 5; ++l) {
#pragma unroll
            for (int j = 0; j < 32; ++j) {
                float a = bih[l * 32 + j] + bhh[l * 32 + j];
#pragma unroll
                for (int k = 0; k < 32; ++k)
                    a = fmaf(WihR[((size_t)(l - 1) * 32 + j) * 32 + k], h[l - 1][k], a);
#pragma unroll
                for (int k = 0; k < 32; ++k)
                    a = fmaf(Whh[((size_t)l * 32 + j) * 32 + k], h[l][k], a);
                y[j] = fast_tanh(a);
            }
#pragma unroll
            for (int j = 0; j < 32; ++j) h[l][j] = y[j];
        }
        // store final-layer output, feature-major (coalesced: consecutive lanes -> consecutive samples)
#pragma unroll
        for (int j = 0; j < 32; ++j)
            Y[(size_t)(t * 32 + j) * Bs + bl] = h[4][j];
    }
}

// ---------------- FC layer: Out[M][Bs] = act(W[M,K] @ In[K][Bs] + bias), chunk-local ----------------
template <int M, int K, int WJ, int WS, int RELU>
__global__ __launch_bounds__(512, 2) void fc_kernel(
    const float* __restrict__ W, const float* __restrict__ bias,
    const float* __restrict__ In, float* __restrict__ Out, int Bs)
{
    constexpr int MW = M / WJ;     // output rows per wave
    constexpr int BN = 64 * WS;    // samples per block
    constexpr int KC = 32;         // k-chunk
    __shared__ float lds[KC * BN];

    const int tid  = threadIdx.x;
    const int wave = tid >> 6;
    const int lane = tid & 63;
    // force wave-uniform j0 into SGPR so weight reads become s_load
    const int wj = __builtin_amdgcn_readfirstlane(wave / WS);
    const int ws = wave % WS;
    const int sampBase = blockIdx.x * BN;
    const int samp = sampBase + ws * 64 + lane;
    const int j0 = wj * MW;

    float acc[MW];
#pragma unroll
    for (int j = 0; j < MW; ++j) acc[j] = bias[j0 + j];

    constexpr int NCHUNK = K / KC;
    constexpr int NV4 = KC * BN / 4;  // float4 elements per chunk stage
#pragma unroll 1
    for (int c = 0; c < NCHUNK; ++c) {
        __syncthreads();
#pragma unroll
        for (int i = 0; i < NV4 / 512; ++i) {
            int f = tid + i * 512;
            int row = f / (BN / 4);
            int col4 = f % (BN / 4);
            const float4 v = *reinterpret_cast<const float4*>(
                &In[(size_t)(c * KC + row) * Bs + sampBase + col4 * 4]);
            *reinterpret_cast<float4*>(&lds[row * BN + col4 * 4]) = v;
        }
        __syncthreads();
        float xr[KC];
#pragma unroll
        for (int k = 0; k < KC; ++k) xr[k] = lds[k * BN + ws * 64 + lane];
#pragma unroll
        for (int j = 0; j < MW; ++j) {
            const float* wrow = &W[(size_t)(j0 + j) * K + c * KC];
#pragma unroll
            for (int k = 0; k < KC; ++k) acc[j] = fmaf(wrow[k], xr[k], acc[j]);
        }
    }
#pragma unroll
    for (int j = 0; j < MW; ++j) {
        float v = acc[j];
        if (RELU) v = fmaxf(v, 0.0f);
        Out[(size_t)(j0 + j) * Bs + samp] = v;
    }
}

// ---------------- final dot layer: out[base+b] = W5 . In[:, b] + b5 ----------------
__global__ __launch_bounds__(256) void fc5_kernel(
    const float* __restrict__ W5, const float* __restrict__ b5,
    const float* __restrict__ In, float* __restrict__ Out, int Bs)
{
    const int b = blockIdx.x * 256 + threadIdx.x;
    float acc = b5[0];
#pragma unroll
    for (int k = 0; k < 64; ++k)
        acc = fmaf(W5[k], In[(size_t)k * Bs + b], acc);
    Out[b] = acc;
}

extern "C" void kernel_launch(void* const* d_in, const int* in_sizes, int n_in,
                              void* d_out, int out_size, void* d_ws, size_t ws_size,
                              hipStream_t stream)
{
    const float* x    = (const float*)d_in[0];
    const float* h0   = (const float*)d_in[1];
    const float* Wih0 = (const float*)d_in[2];
    const float* WihR = (const float*)d_in[3];
    const float* Whh  = (const float*)d_in[4];
    const float* bih  = (const float*)d_in[5];
    const float* bhh  = (const float*)d_in[6];
    const float* W1 = (const float*)d_in[7];
    const float* b1 = (const float*)d_in[8];
    const float* W2 = (const float*)d_in[9];
    const float* b2 = (const float*)d_in[10];
    const float* W3 = (const float*)d_in[11];
    const float* b3 = (const float*)d_in[12];
    const float* W4 = (const float*)d_in[13];
    const float* b4 = (const float*)d_in[14];
    const float* W5 = (const float*)d_in[15];
    const float* b5 = (const float*)d_in[16];
    float* out = (float*)d_out;

    // Peak simultaneous footprint per chunk of Bc samples:
    //   Y [960][Bc] + A1 [512][Bc]  ->  (960+512)*4 = 5888 bytes/sample.
    // Pick the largest power-of-two chunk that fits ws_size.
    size_t Bc = BTOT;
    while (Bc > 1024 && (size_t)5888 * Bc > ws_size) Bc >>= 1;
    const int Bs = (int)Bc;

    float* Y  = (float*)d_ws;            // [960][Bc]
    float* A1 = Y + (size_t)960 * Bc;    // [512][Bc]
    float* A2 = (float*)d_ws;            // [256][Bc]  overlays Y  (dead after fc1)
    float* A3 = A1;                      // [128][Bc]  overlays A1 (dead after fc2)
    float* A4 = (float*)d_ws;            // [64][Bc]   overlays A2 (dead after fc3)

    for (size_t base = 0; base < BTOT; base += Bc) {
        rnn_kernel<<<Bs / 256, 256, 0, stream>>>(x, h0, Wih0, WihR, Whh, bih, bhh,
                                                 Y, (int)base, Bs);
        fc_kernel<512, 960, 8, 1, 1><<<Bs / 64, 512, 0, stream>>>(W1, b1, Y, A1, Bs);
        fc_kernel<256, 512, 8, 1, 1><<<Bs / 64, 512, 0, stream>>>(W2, b2, A1, A2, Bs);
        fc_kernel<128, 256, 4, 2, 1><<<Bs / 128, 512, 0, stream>>>(W3, b3, A2, A3, Bs);
        fc_kernel<64, 128, 2, 4, 1><<<Bs / 256, 512, 0, stream>>>(W4, b4, A3, A4, Bs);
        fc5_kernel<<<Bs / 256, 256, 0, stream>>>(W5, b5, A4, out + base, Bs);
    }
}

// Round 5
// 8202.122 us; speedup vs baseline: 1.5544x; 1.5544x over previous
//
#include <hip/hip_runtime.h>

typedef __attribute__((ext_vector_type(8))) short          short8;  // bf16x8 MFMA frag (4 VGPR)
typedef __attribute__((ext_vector_type(4))) float          f32x4;   // MFMA accumulator
typedef __attribute__((ext_vector_type(8))) unsigned short us8;

#define BTOT 65536
#define TT   30

static __device__ __forceinline__ unsigned short f2bf(float f) {
    unsigned u = __float_as_uint(f);
    u = (u + 0x7FFFu + ((u >> 16) & 1u)) >> 16;   // RNE; finite values only
    return (unsigned short)u;
}
static __device__ __forceinline__ float bf2f(unsigned short h) {
    return __uint_as_float(((unsigned)h) << 16);
}

__device__ __forceinline__ float fast_tanh(float v) {
    float e = __builtin_amdgcn_exp2f(v * 2.885390081777927f);
    float r = __builtin_amdgcn_rcpf(e + 1.0f);
    return fmaf(-2.0f, r, 1.0f);
}

// ---------------- weight splitter: fp32 -> bf16 hi/mid/lo ----------------
__global__ void split_kernel(const float* __restrict__ src, unsigned short* __restrict__ dh,
                             unsigned short* __restrict__ dm, unsigned short* __restrict__ dl, int n) {
    int i = blockIdx.x * 256 + threadIdx.x;
    if (i < n) {
        float v = src[i];
        unsigned short a = f2bf(v); float r1 = v - bf2f(a);
        unsigned short b = f2bf(r1);
        unsigned short c = f2bf(r1 - bf2f(b));
        dh[i] = a; dm[i] = b; dl[i] = c;
    }
}

// ---------------- RNN: fused 5 layers, 1 thread = 1 sample; split-bf16 epilogue ----------------
// Y stored sample-major [Bs][960] as 3 bf16 arrays (hi/mid/lo).
__global__ __launch_bounds__(256, 1) void rnn_kernel(
    const float* __restrict__ x, const float* __restrict__ h0,
    const float* __restrict__ Wih0, const float* __restrict__ WihR,
    const float* __restrict__ Whh, const float* __restrict__ bih,
    const float* __restrict__ bhh,
    unsigned short* __restrict__ Yh, unsigned short* __restrict__ Ym,
    unsigned short* __restrict__ Yl, int base, int Bs)
{
    const int bl = blockIdx.x * 256 + threadIdx.x;
    const int b  = base + bl;
    float h[5][32];
#pragma unroll
    for (int l = 0; l < 5; ++l)
#pragma unroll
        for (int j = 0; j < 32; ++j)
            h[l][j] = h0[((size_t)l * BTOT + b) * 32 + j];

    const float* xb = x + (size_t)b * (TT * 3);

#pragma unroll 1
    for (int t = 0; t < TT; ++t) {
        const float in0 = xb[t * 3 + 0];
        const float in1 = xb[t * 3 + 1];
        const float in2 = xb[t * 3 + 2];
        float y[32];
#pragma unroll
        for (int j = 0; j < 32; ++j) {
            float a = bih[j] + bhh[j];
            a = fmaf(Wih0[j * 3 + 0], in0, a);
            a = fmaf(Wih0[j * 3 + 1], in1, a);
            a = fmaf(Wih0[j * 3 + 2], in2, a);
#pragma unroll
            for (int k = 0; k < 32; ++k)
                a = fmaf(Whh[j * 32 + k], h[0][k], a);
            y[j] = fast_tanh(a);
        }
#pragma unroll
        for (int j = 0; j < 32; ++j) h[0][j] = y[j];
#pragma unroll
        for (int l = 1; l < 5; ++l) {
#pragma unroll
            for (int j = 0; j < 32; ++j) {
                float a = bih[l * 32 + j] + bhh[l * 32 + j];
#pragma unroll
                for (int k = 0; k < 32; ++k)
                    a = fmaf(WihR[((size_t)(l - 1) * 32 + j) * 32 + k], h[l - 1][k], a);
#pragma unroll
                for (int k = 0; k < 32; ++k)
                    a = fmaf(Whh[((size_t)l * 32 + j) * 32 + k], h[l][k], a);
                y[j] = fast_tanh(a);
            }
#pragma unroll
            for (int j = 0; j < 32; ++j) h[l][j] = y[j];
        }
        // split-bf16 store, 16B vector stores (sample-major, contiguous per thread)
        us8 th, tm, tl;
#pragma unroll
        for (int j = 0; j < 32; ++j) {
            float v = h[4][j];
            unsigned short a = f2bf(v); float r1 = v - bf2f(a);
            unsigned short m = f2bf(r1);
            unsigned short c = f2bf(r1 - bf2f(m));
            th[j & 7] = a; tm[j & 7] = m; tl[j & 7] = c;
            if ((j & 7) == 7) {
                const size_t o = (size_t)bl * 960 + t * 32 + (j / 8) * 8;
                *(us8*)(Yh + o) = th; *(us8*)(Ym + o) = tm; *(us8*)(Yl + o) = tl;
            }
        }
    }
}

// ---------------- FC via MFMA, 3-way split-bf16 (6 products) ----------------
// Out[b][m] = act( sum_k In[b][k] * W[m][k] + bias[m] ), In/W/Out all [rows][K] bf16 h/m/l.
// Block: 8 waves = SW sample-quadrants x FW feature-quadrants; wave tile 64 samples x 64 feats.
// A-frag lane l: In[sb+st*16+(l&15)][kc+(l>>4)*8 + j]; B-frag lane l: W[fb+ft*16+(l&15)][same k].
// C lane l: row(sample)=(l>>4)*4+r, col(feat)=l&15.
template <int M, int K, int FW, int SW, int RELU>
__global__ __launch_bounds__(512, 2) void fcm_kernel(
    const unsigned short* __restrict__ Wh, const unsigned short* __restrict__ Wm,
    const unsigned short* __restrict__ Wl, const float* __restrict__ bias,
    const unsigned short* __restrict__ Ih, const unsigned short* __restrict__ Im,
    const unsigned short* __restrict__ Il,
    unsigned short* __restrict__ Oh, unsigned short* __restrict__ Om,
    unsigned short* __restrict__ Ol)
{
    const int lane = threadIdx.x & 63;
    const int wv   = threadIdx.x >> 6;           // 0..7
    const int fq   = wv % FW;
    const int sq   = wv / FW;
    const int sb   = blockIdx.x * (SW * 64) + sq * 64;
    const int fb   = fq * 64;
    const int lr   = lane & 15;
    const int lk   = (lane >> 4) * 8;

    f32x4 acc[4][4] = {};

#pragma unroll 1
    for (int kc = 0; kc < K; kc += 32) {
        short8 a0[4], a1[4], a2[4];
#pragma unroll
        for (int st = 0; st < 4; ++st) {
            const size_t ro = (size_t)(sb + st * 16 + lr) * K + kc + lk;
            a0[st] = *(const short8*)(Ih + ro);
            a1[st] = *(const short8*)(Im + ro);
            a2[st] = *(const short8*)(Il + ro);
        }
#pragma unroll
        for (int ft = 0; ft < 4; ++ft) {
            const size_t ro = (size_t)(fb + ft * 16 + lr) * K + kc + lk;
            const short8 b0 = *(const short8*)(Wh + ro);
            const short8 b1 = *(const short8*)(Wm + ro);
            const short8 b2 = *(const short8*)(Wl + ro);
#pragma unroll
            for (int st = 0; st < 4; ++st) {
                f32x4 c = acc[st][ft];
                c = __builtin_amdgcn_mfma_f32_16x16x32_bf16(a0[st], b0, c, 0, 0, 0);
                c = __builtin_amdgcn_mfma_f32_16x16x32_bf16(a0[st], b1, c, 0, 0, 0);
                c = __builtin_amdgcn_mfma_f32_16x16x32_bf16(a1[st], b0, c, 0, 0, 0);
                c = __builtin_amdgcn_mfma_f32_16x16x32_bf16(a0[st], b2, c, 0, 0, 0);
                c = __builtin_amdgcn_mfma_f32_16x16x32_bf16(a2[st], b0, c, 0, 0, 0);
                c = __builtin_amdgcn_mfma_f32_16x16x32_bf16(a1[st], b1, c, 0, 0, 0);
                acc[st][ft] = c;
            }
        }
    }

#pragma unroll
    for (int st = 0; st < 4; ++st)
#pragma unroll
        for (int ft = 0; ft < 4; ++ft) {
            const int feat = fb + ft * 16 + lr;
            const float bv = bias[feat];
#pragma unroll
            for (int r = 0; r < 4; ++r) {
                const int smp = sb + st * 16 + (lane >> 4) * 4 + r;
                float v = acc[st][ft][r] + bv;
                if (RELU) v = fmaxf(v, 0.0f);
                unsigned short hh = f2bf(v);  float r1 = v - bf2f(hh);
                unsigned short mm = f2bf(r1);
                unsigned short ll = f2bf(r1 - bf2f(mm));
                const size_t o = (size_t)smp * M + feat;
                Oh[o] = hh; Om[o] = mm; Ol[o] = ll;
            }
        }
}

// ---------------- final dot: out[b] = W5 . (Ah+Am+Al)[b,:] + b5 ----------------
__global__ __launch_bounds__(256) void fc5_kernel(
    const float* __restrict__ W5, const float* __restrict__ b5,
    const unsigned short* __restrict__ Ah, const unsigned short* __restrict__ Am,
    const unsigned short* __restrict__ Al, float* __restrict__ Out, int base)
{
    const int bl = blockIdx.x * 256 + threadIdx.x;
    const size_t o = (size_t)bl * 64;
    float acc = b5[0];
#pragma unroll
    for (int k = 0; k < 64; ++k) {
        float v = bf2f(Ah[o + k]) + bf2f(Am[o + k]) + bf2f(Al[o + k]);
        acc = fmaf(v, W5[k], acc);
    }
    Out[base + bl] = acc;
}

extern "C" void kernel_launch(void* const* d_in, const int* in_sizes, int n_in,
                              void* d_out, int out_size, void* d_ws, size_t ws_size,
                              hipStream_t stream)
{
    const float* x    = (const float*)d_in[0];
    const float* h0   = (const float*)d_in[1];
    const float* Wih0 = (const float*)d_in[2];
    const float* WihR = (const float*)d_in[3];
    const float* Whh  = (const float*)d_in[4];
    const float* bih  = (const float*)d_in[5];
    const float* bhh  = (const float*)d_in[6];
    const float* W1 = (const float*)d_in[7];   const float* b1 = (const float*)d_in[8];
    const float* W2 = (const float*)d_in[9];   const float* b2 = (const float*)d_in[10];
    const float* W3 = (const float*)d_in[11];  const float* b3 = (const float*)d_in[12];
    const float* W4 = (const float*)d_in[13];  const float* b4 = (const float*)d_in[14];
    const float* W5 = (const float*)d_in[15];  const float* b5 = (const float*)d_in[16];
    float* out = (float*)d_out;

    // ---- bump allocator on d_ws ----
    size_t off = 0;
    auto alloc = [&](size_t bytes) -> void* {
        off = (off + 255) & ~(size_t)255;
        void* p = (char*)d_ws + off;
        off += bytes;
        return p;
    };
    // weight split areas (persistent across chunks)
    const int nW1 = 512 * 960, nW2 = 256 * 512, nW3 = 128 * 256, nW4 = 64 * 128;
    unsigned short *W1h = (unsigned short*)alloc((size_t)nW1 * 2), *W1m = (unsigned short*)alloc((size_t)nW1 * 2), *W1l = (unsigned short*)alloc((size_t)nW1 * 2);
    unsigned short *W2h = (unsigned short*)alloc((size_t)nW2 * 2), *W2m = (unsigned short*)alloc((size_t)nW2 * 2), *W2l = (unsigned short*)alloc((size_t)nW2 * 2);
    unsigned short *W3h = (unsigned short*)alloc((size_t)nW3 * 2), *W3m = (unsigned short*)alloc((size_t)nW3 * 2), *W3l = (unsigned short*)alloc((size_t)nW3 * 2);
    unsigned short *W4h = (unsigned short*)alloc((size_t)nW4 * 2), *W4m = (unsigned short*)alloc((size_t)nW4 * 2), *W4l = (unsigned short*)alloc((size_t)nW4 * 2);
    const size_t fixed = off + 4096;

    // chunk size: region0 = 3 * Bc*960*2 (Y, later A2, A4); region1 = 3 * Bc*512*2 (A1, later A3)
    size_t Bc = BTOT;
    while (Bc > 1024 && fixed + (size_t)8832 * Bc > ws_size) Bc >>= 1;
    const int Bs = (int)Bc;

    unsigned short *Yh = (unsigned short*)alloc(Bc * 960 * 2), *Ym = (unsigned short*)alloc(Bc * 960 * 2), *Yl = (unsigned short*)alloc(Bc * 960 * 2);
    unsigned short *A1h = (unsigned short*)alloc(Bc * 512 * 2), *A1m = (unsigned short*)alloc(Bc * 512 * 2), *A1l = (unsigned short*)alloc(Bc * 512 * 2);
    // overlays: A2 (256) in Y strips; A3 (128) in A1 strips; A4 (64) back in Y strips
    unsigned short *A2h = Yh,  *A2m = Ym,  *A2l = Yl;
    unsigned short *A3h = A1h, *A3m = A1m, *A3l = A1l;
    unsigned short *A4h = Yh,  *A4m = Ym,  *A4l = Yl;

    // split weights once per launch
    split_kernel<<<(nW1 + 255) / 256, 256, 0, stream>>>(W1, W1h, W1m, W1l, nW1);
    split_kernel<<<(nW2 + 255) / 256, 256, 0, stream>>>(W2, W2h, W2m, W2l, nW2);
    split_kernel<<<(nW3 + 255) / 256, 256, 0, stream>>>(W3, W3h, W3m, W3l, nW3);
    split_kernel<<<(nW4 + 255) / 256, 256, 0, stream>>>(W4, W4h, W4m, W4l, nW4);

    for (size_t base = 0; base < BTOT; base += Bc) {
        rnn_kernel<<<Bs / 256, 256, 0, stream>>>(x, h0, Wih0, WihR, Whh, bih, bhh,
                                                 Yh, Ym, Yl, (int)base, Bs);
        fcm_kernel<512, 960, 8, 1, 1><<<Bs / 64, 512, 0, stream>>>(
            W1h, W1m, W1l, b1, Yh, Ym, Yl, A1h, A1m, A1l);
        fcm_kernel<256, 512, 4, 2, 1><<<Bs / 128, 512, 0, stream>>>(
            W2h, W2m, W2l, b2, A1h, A1m, A1l, A2h, A2m, A2l);
        fcm_kernel<128, 256, 2, 4, 1><<<Bs / 256, 512, 0, stream>>>(
            W3h, W3m, W3l, b3, A2h, A2m, A2l, A3h, A3m, A3l);
        fcm_kernel<64, 128, 1, 8, 1><<<Bs / 512, 512, 0, stream>>>(
            W4h, W4m, W4l, b4, A3h, A3m, A3l, A4h, A4m, A4l);
        fc5_kernel<<<Bs / 256, 256, 0, stream>>>(W5, b5, A4h, A4m, A4l, out, (int)base);
    }
}